// Round 7
// baseline (1182.104 us; speedup 1.0000x reference)
//
#include <hip/hip_runtime.h>

#define HH 512
#define WW 512
#define HWP (HH * WW)

typedef unsigned short bf16_t;
typedef short bf16x8 __attribute__((ext_vector_type(8)));
typedef float f32x4 __attribute__((ext_vector_type(4)));
typedef unsigned short us4 __attribute__((ext_vector_type(4)));
typedef unsigned short us8 __attribute__((ext_vector_type(8)));

__device__ __forceinline__ float bf2f(bf16_t h) {
    union { unsigned int u; float f; } v; v.u = ((unsigned int)h) << 16; return v.f;
}
__device__ __forceinline__ bf16_t f2bf(float f) {
    union { float f; unsigned int u; } v; v.f = f;
    unsigned int r = (v.u + 0x7FFFu + ((v.u >> 16) & 1u)) >> 16;
    return (bf16_t)r;
}

// Weight prep for ALL layers in one dispatch (+ zero page at the tail).
// Layout per layer: bf16 [9][KS][COTF][64 lanes][8].
__global__ __launch_bounds__(256) void wprep_all(
    const float* __restrict__ w1, const float* __restrict__ w2,
    const float* __restrict__ w3, const float* __restrict__ w4,
    const float* __restrict__ w5, const float* __restrict__ w6,
    bf16_t* __restrict__ dst)
{
    int i = blockIdx.x * 256 + threadIdx.x;
    if (i >= 350720) return;
    if (i >= 350208) { dst[i] = 0; return; }   // zero page
    const float* w; int Cout, Cin, COTF, KS, perm, base;
    if (i < 18432)       { w = w1; base = 0;      Cout = 64;  Cin = 5;   COTF = 4; KS = 1; perm = 0; }
    else if (i < 92160)  { w = w2; base = 18432;  Cout = 128; Cin = 64;  COTF = 8; KS = 2; perm = 0; }
    else if (i < 202752) { w = w3; base = 92160;  Cout = 81;  Cin = 128; COTF = 6; KS = 4; perm = 0; }
    else if (i < 294912) { w = w4; base = 202752; Cout = 64;  Cin = 160; COTF = 4; KS = 5; perm = 1; }
    else if (i < 331776) { w = w5; base = 294912; Cout = 64;  Cin = 64;  COTF = 4; KS = 2; perm = 0; }
    else                 { w = w6; base = 331776; Cout = 27;  Cin = 64;  COTF = 2; KS = 2; perm = 0; }
    int r = i - base;
    int j = r & 7;
    int lane = (r >> 3) & 63;
    int cot = (r >> 9) % COTF;
    int rest = r / (512 * COTF);      // = tap*KS + ks
    int ks = rest % KS, tap = rest / KS;
    int col = lane & 15, hi = lane >> 4;
    int co = cot * 16 + col;
    int ci = ks * 32 + hi * 8 + j;
    float v = 0.f;
    if (co < Cout && ci < Cin) {
        int rci = ci;
        if (perm) rci = (ci < 128) ? ci + 5 : (ci < 133 ? ci - 128 : ci);
        v = w[((size_t)co * Cin + rci) * 9 + tap];
    }
    dst[i] = f2bf(v);
}

// DIRECT-LOAD implicit-GEMM 3x3 SAME conv v7: NO LDS, NO barriers, NO
// staging. In the slab layout [C/32][512][512][32], a wave's B-fragment
// for (row,dx) is 16 consecutive pixels x 64B = 1KB contiguous: lane
// (col,hi) reads bytes hi*16 of pixel col -- the natural coalesced
// global load IS the MFMA fragment. dy-reuse (3x) and cross-wave reuse
// are L2-resident (per-XCD working set ~1.6MB << 4MB), so LDS staging
// bought nothing but the 2-phase vmcnt/barrier convoy.
// EVIDENCE for removal: conv2 block lifetime 21.5k cy vs ~2.8k MFMA +
// ~5k VALU demand; all pipes <35%; SEVEN schedule/locality levers were
// neutral-or-worse (R1 counted-vmcnt, R2 occ-3 spill, R3 y-persist L2
// thrash, R4 z-fold, R5 LDS-read halving, R6 3-buffer lead) == the
// 2-phase lockstep itself was the wall (m233: ~72% structural cost).
// Waves now run barrier-free (latency self-hedging, m114 overlap).
// Bounds/zero-fill: per-lane pointer select to zero page. conv1's
// unwritten frame-slab chunks handled by (hi < cinCh).
// Block = 256 thr = 4 waves; block tile = 4 rows x 64 px; wave owns
// 16 px x 4 rows (v5 mapping). ZX folds the co z-split into blockIdx.x.
// fuseOut != nullptr (ww3 only): fused combine epilogue -> gp_pred/avg.
template<int COT, int KS, int ZX>
__global__ __launch_bounds__(256, 2) void tconv(
    const bf16_t* __restrict__ in, size_t inImgStride,
    const bf16_t* __restrict__ wt, const float* __restrict__ bias,
    bf16_t* __restrict__ out, size_t outImgStride,
    int COTF, int Cout, int relu, const bf16_t* __restrict__ zp,
    int cinCh, const bf16_t* __restrict__ catp,
    float* __restrict__ fuseOut, int img0)
{
    const int tid = threadIdx.x;
    const int wave = tid >> 6, lane = tid & 63;
    const int col = lane & 15, hi = lane >> 4;
    const int img = blockIdx.y >> 7;
    const int yb0 = (blockIdx.y & 127) * 4;
    const int xb = (ZX ? (blockIdx.x >> 1) : blockIdx.x) * 64;
    const int czbase = (ZX ? (blockIdx.x & 1) : blockIdx.z) * COT;
    const size_t slab = (size_t)HH * WW * 32;

    in += (size_t)img * inImgStride;
    out += (size_t)img * outImgStride;

    // Per-lane B-load decomposition: row part (6 rows) x dx part (3).
    int ybase[6]; bool vy[6];
#pragma unroll
    for (int br = 0; br < 6; ++br) {
        int yin = yb0 - 1 + br;
        vy[br] = (unsigned)yin < (unsigned)HH;
        ybase[br] = yin * (WW * 32);
    }
    int xoff[3]; bool vx[3];
#pragma unroll
    for (int dx = 0; dx < 3; ++dx) {
        int gx = xb - 1 + wave * 16 + col + dx;
        vx[dx] = ((unsigned)gx < (unsigned)WW) && (hi < cinCh);
        xoff[dx] = gx * 32 + hi * 8;
    }

    f32x4 acc[4][COT] = {};      // acc[r][c]: output row yb0+r, oc tile c
    bf16x8 a[9][COT];

    auto ALOAD = [&](int ks) {
#pragma unroll
        for (int t = 0; t < 9; ++t) {
#pragma unroll
            for (int c = 0; c < COT; ++c)
                a[t][c] = *(const bf16x8*)(wt
                    + (((size_t)t * KS + ks) * COTF + czbase + c) * 512 + lane * 8);
        }
    };

    for (int ks = 0; ks < KS; ++ks) {
        ALOAD(ks);
        const bf16_t* base = in + (size_t)ks * slab;
#pragma unroll
        for (int dx = 0; dx < 3; ++dx) {
            bf16x8 b[6];
#pragma unroll
            for (int br = 0; br < 6; ++br) {
                const bf16_t* p = (vy[br] && vx[dx])
                                  ? base + ybase[br] + xoff[dx] : zp;
                b[br] = *(const bf16x8*)p;
            }
#pragma unroll
            for (int dy = 0; dy < 3; ++dy) {
#pragma unroll
                for (int c = 0; c < COT; ++c) {
#pragma unroll
                    for (int r = 0; r < 4; ++r)
                        acc[r][c] = __builtin_amdgcn_mfma_f32_16x16x32_bf16(
                            a[dy * 3 + dx][c], b[r + dy], acc[r][c], 0, 0, 0);
                }
            }
        }
    }

    const int x = xb + wave * 16 + col;

    if (fuseOut) {
        // Fused combine (ww3): weight ch = sample idx s (0..23),
        // sample = cat ch 5+s, group g = s/6. shfl over hi-quads
        // (lane = hi*16+col; xor 16/32 flips hi bits, col preserved).
        int gimg = img0 + img;
        const bf16_t* catim = catp + (size_t)img * inImgStride;
#pragma unroll
        for (int r = 0; r < 4; ++r) {
            int y = yb0 + r;
            const bf16_t* cp = catim + ((size_t)y * WW + x) * 32;
            float p[4] = {0.f, 0.f, 0.f, 0.f};
#pragma unroll
            for (int c = 0; c < COT; ++c) {
                int chb = (czbase + c) * 16 + hi * 4;
#pragma unroll
                for (int j = 0; j < 4; ++j) {
                    int ch = chb + j;
                    if (ch < 24) {
                        float wv = fmaxf(acc[r][c][j] + bias[ch], 0.f);
                        p[ch / 6] += wv * bf2f(cp[5 + ch]);
                    }
                }
            }
#pragma unroll
            for (int g = 0; g < 4; ++g) {
                p[g] += __shfl_xor(p[g], 16);
                p[g] += __shfl_xor(p[g], 32);
            }
            if (hi == 0) {
                size_t pix = (size_t)y * WW + x;
                float tot = 0.f;
#pragma unroll
                for (int g = 0; g < 4; ++g) {
                    float gp = 4.f * p[g];
                    fuseOut[((size_t)gimg * 4 + g) * HWP + pix] = gp;
                    tot += gp;
                }
                fuseOut[(size_t)16 * HWP + (size_t)gimg * HWP + pix] = tot / 27.f;
            }
        }
        return;
    }

    // Epilogue: slab-layout NHWC-32 store; wave owns a 16-px strip x 4 rows.
#pragma unroll
    for (int c = 0; c < COT; ++c) {
        int chbase = (czbase + c) * 16 + hi * 4;
        int slice = chbase >> 5, rem = chbase & 31;
        float bv[4];
#pragma unroll
        for (int j = 0; j < 4; ++j) {
            int co = chbase + j;
            bv[j] = (co < Cout) ? bias[co] : 0.f;
        }
#pragma unroll
        for (int r = 0; r < 4; ++r) {
            int y = yb0 + r;
            us4 o;
#pragma unroll
            for (int j = 0; j < 4; ++j) {
                float v = acc[r][c][j] + bv[j];
                if (relu) v = fmaxf(v, 0.f);
                o[j] = f2bf(v);
            }
            *(us4*)(out + (((size_t)slice * HH + y) * WW + x) * 32 + rem) = o;
        }
    }
}

// frames fp32 NCHW -> slab [1][512][512][32] bf16, CHUNK 0 ONLY (ch 0..4
// real, 5..7 zero). Chunks 1..3 are never written: conv1 reads them
// as zero via (hi < cinCh) lane masking, saving 192 MB of zero writes.
__global__ __launch_bounds__(256) void tr_fr32(
    const float* __restrict__ fr0, int img0,
    bf16_t* __restrict__ dst0, size_t stride)
{
    int img = blockIdx.y;
    int i = blockIdx.x * 256 + threadIdx.x;   // 0..262143, exact
    const float* fr = fr0 + (size_t)(img0 + img) * 5 * HWP;
    bf16_t* dst = dst0 + (size_t)img * stride;
    us8 v0 = {};
#pragma unroll
    for (int c = 0; c < 5; ++c) v0[c] = f2bf(fr[(size_t)c * HWP + i]);
    *(us8*)(dst + (size_t)i * 32) = v0;
}

// Fused sampler: trilinear 27-sample + frame-channel fill, full 32-ch
// vectorized output. IN-PLACE: cat slab == OF slab 0 (each thread reads
// its pixel's 96 offset channels BEFORE writing its pixel's 32 cat
// channels; no cross-pixel dependence, so the overwrite is safe).
__global__ __launch_bounds__(256, 4) void sample27f(
    const float* __restrict__ fr0, int img0,
    const bf16_t* __restrict__ of0, size_t stride,
    bf16_t* __restrict__ cat0)
{
    int img = blockIdx.y;
    int i = blockIdx.x * 256 + threadIdx.x;
    int y = i >> 9, x = i & 511;
    const float* f = fr0 + (size_t)(img0 + img) * 5 * HWP;
    const bf16_t* off = of0 + (size_t)img * stride;
    bf16_t* cat = cat0 + (size_t)img * stride;

    us8 ov[12];
#pragma unroll
    for (int sl = 0; sl < 3; ++sl)
#pragma unroll
        for (int c = 0; c < 4; ++c)
            ov[sl * 4 + c] = *(const us8*)(off
                + (((size_t)sl * HH + y) * WW + x) * 32 + c * 8);

    us8 outv[4];
#pragma unroll
    for (int c = 0; c < 5; ++c)
        outv[0][c] = f2bf(f[(size_t)c * HWP + i]);

#pragma unroll
    for (int s = 0; s < 27; ++s) {
        float dt  = bf2f((bf16_t)ov[(3 * s) >> 3][(3 * s) & 7]);
        float dyo = bf2f((bf16_t)ov[(3 * s + 1) >> 3][(3 * s + 1) & 7]);
        float dxo = bf2f((bf16_t)ov[(3 * s + 2) >> 3][(3 * s + 2) & 7]);
        float tc = dt + (float)(s / 9 + 1);
        float yc = dyo + (float)((s / 3) % 3 - 1) + (float)y;
        float xc = dxo + (float)(s % 3 - 1) + (float)x;
        tc = fminf(fmaxf(tc, 0.f), 4.f);
        yc = fminf(fmaxf(yc, 0.f), 511.f);
        xc = fminf(fmaxf(xc, 0.f), 511.f);
        float t0f = floorf(tc), y0f = floorf(yc), x0f = floorf(xc);
        float wt = tc - t0f, wy = yc - y0f, wx = xc - x0f;
        int t0 = (int)t0f, y0 = (int)y0f, x0 = (int)x0f;
        int t1 = min(t0 + 1, 4), y1 = min(y0 + 1, 511), x1 = min(x0 + 1, 511);
        float c000 = f[((size_t)t0 * HH + y0) * WW + x0];
        float c001 = f[((size_t)t0 * HH + y0) * WW + x1];
        float c010 = f[((size_t)t0 * HH + y1) * WW + x0];
        float c011 = f[((size_t)t0 * HH + y1) * WW + x1];
        float c100 = f[((size_t)t1 * HH + y0) * WW + x0];
        float c101 = f[((size_t)t1 * HH + y0) * WW + x1];
        float c110 = f[((size_t)t1 * HH + y1) * WW + x0];
        float c111 = f[((size_t)t1 * HH + y1) * WW + x1];
        float c00 = c000 * (1.f - wx) + c001 * wx;
        float c01 = c010 * (1.f - wx) + c011 * wx;
        float c10 = c100 * (1.f - wx) + c101 * wx;
        float c11 = c110 * (1.f - wx) + c111 * wx;
        float c0 = c00 * (1.f - wy) + c01 * wy;
        float c1 = c10 * (1.f - wy) + c11 * wy;
        int ch = 5 + s;
        outv[ch >> 3][ch & 7] = f2bf(c0 * (1.f - wt) + c1 * wt);
    }

    us8* o = (us8*)(cat + ((size_t)y * WW + x) * 32);
    o[0] = outv[0]; o[1] = outv[1]; o[2] = outv[2]; o[3] = outv[3];
}

static inline int cdiv(int a, int b) { return (a + b - 1) / b; }

extern "C" void kernel_launch(void* const* d_in, const int* in_sizes, int n_in,
                              void* d_out, int out_size, void* d_ws, size_t ws_size,
                              hipStream_t stream)
{
    const float* frames = (const float*)d_in[0];
    const float* ow1 = (const float*)d_in[1];
    const float* ob1 = (const float*)d_in[2];
    const float* ow2 = (const float*)d_in[3];
    const float* ob2 = (const float*)d_in[4];
    const float* ow3 = (const float*)d_in[5];
    const float* ob3 = (const float*)d_in[6];
    const float* ww1 = (const float*)d_in[7];
    const float* wb1 = (const float*)d_in[8];
    const float* ww2 = (const float*)d_in[9];
    const float* wb2 = (const float*)d_in[10];
    const float* ww3 = (const float*)d_in[11];
    const float* wb3 = (const float*)d_in[12];
    float* out = (float*)d_out;

    bf16_t* Wp = (bf16_t*)d_ws;
    const size_t wo1 = 0;          // conv1: KS1 COTF4
    const size_t wo2 = 18432;      // conv2: KS2 COTF8
    const size_t wo3 = 92160;      // conv3: KS4 COTF6
    const size_t wo4 = 202752;     // ww1:   KS5 COTF4
    const size_t wo5 = 294912;     // ww2:   KS2 COTF4
    const size_t wo6 = 331776;     // ww3:   KS2 COTF2
    const size_t wzp = 350208;     // zero page (1 KB)
    const size_t wtot = 350720;

    // 7-slab aliased per-image workspace (liveness-verified):
    //   S0..S3: feat (conv2 out) -> W2 (S0..S1)
    //   S4..S6: F1 (S4..S5), FR (S6, chunk0 only) -> OF (S4..S6) ->
    //           cat (S4, in-place sampler) / W1 (S5..S6)
    //   ww1 input = S0..S4 contiguous (feat 4 slabs + cat slab).
    //   ww3 writes gp_pred/avg directly (fused combine); S2 unused now.
    const size_t SLAB = (size_t)HH * WW * 32;           // 8,388,608 elems
    const size_t PerImg = 7 * SLAB;                     // 58,720,256 elems

    size_t availElems = ws_size / sizeof(bf16_t);
    int NB = 1;
    if (wtot + 4 * PerImg <= availElems) NB = 4;
    else if (wtot + 2 * PerImg <= availElems) NB = 2;

    bf16_t* ZP = Wp + wzp;
    bf16_t* WS = Wp + wtot;

    wprep_all<<<cdiv(350720, 256), 256, 0, stream>>>(ow1, ow2, ow3, ww1, ww2, ww3, Wp);

    for (int s = 0; s < 4; s += NB) {
        int nb = (4 - s < NB) ? (4 - s) : NB;
        bf16_t* S0 = WS;                 // feat / W2 region
        bf16_t* S2 = WS + 2 * SLAB;      // (spare)
        bf16_t* S4 = WS + 4 * SLAB;      // F1 / OF / cat
        bf16_t* S5 = WS + 5 * SLAB;      // W1
        bf16_t* S6 = WS + 6 * SLAB;      // FR

        // frames -> FR chunk 0 (S6)
        tr_fr32<<<dim3(1024, nb), 256, 0, stream>>>(frames, s, S6, PerImg);
        // conv1: FR 8(pad5) (S6, cinCh=1) -> F1 64 (S4..S5)
        tconv<4, 1, 0><<<dim3(8, 128 * nb, 1), 256, 0, stream>>>(
            S6, PerImg, Wp + wo1, ob1, S4, PerImg, 4, 64, 1, ZP,
            1, nullptr, nullptr, 0);
        // conv2: F1 64 (S4..S5) -> feat 128 (S0..S3), z folded into x
        tconv<4, 2, 1><<<dim3(16, 128 * nb, 1), 256, 0, stream>>>(
            S4, PerImg, Wp + wo2, ob2, S0, PerImg, 8, 128, 1, ZP,
            4, nullptr, nullptr, 0);
        // conv3: feat 128 -> offsets 81(pad96) (S4..S6), no relu, z in x
        tconv<3, 4, 1><<<dim3(16, 128 * nb, 1), 256, 0, stream>>>(
            S0, PerImg, Wp + wo3, ob3, S4, PerImg, 6, 81, 0, ZP,
            4, nullptr, nullptr, 0);
        // fused sampler (+frame fill) -> cat slab IN-PLACE over OF slab 0 (S4)
        sample27f<<<dim3(1024, nb), 256, 0, stream>>>(frames, s, S4, PerImg, S4);
        // ww1: cat 160 (S0..S4, 5 slabs) -> W1 64 (S5..S6)
        tconv<4, 5, 0><<<dim3(8, 128 * nb, 1), 256, 0, stream>>>(
            S0, PerImg, Wp + wo4, wb1, S5, PerImg, 4, 64, 1, ZP,
            4, nullptr, nullptr, 0);
        // ww2: W1 64 (S5..S6) -> W2 64 (S0..S1)
        tconv<4, 2, 0><<<dim3(8, 128 * nb, 1), 256, 0, stream>>>(
            S5, PerImg, Wp + wo5, wb2, S0, PerImg, 4, 64, 1, ZP,
            4, nullptr, nullptr, 0);
        // ww3: W2 64 (S0..S1) -> FUSED combine with cat (S4) -> out
        tconv<2, 2, 0><<<dim3(8, 128 * nb, 1), 256, 0, stream>>>(
            S0, PerImg, Wp + wo6, wb3, S2, PerImg, 2, 27, 1, ZP,
            4, S4, out, s);
    }
}

// Round 8
// 1028.036 us; speedup vs baseline: 1.1499x; 1.1499x over previous
//
#include <hip/hip_runtime.h>

#define HH 512
#define WW 512
#define HWP (HH * WW)

typedef unsigned short bf16_t;
typedef short bf16x8 __attribute__((ext_vector_type(8)));
typedef float f32x4 __attribute__((ext_vector_type(4)));
typedef unsigned short us4 __attribute__((ext_vector_type(4)));
typedef unsigned short us8 __attribute__((ext_vector_type(8)));

__device__ __forceinline__ float bf2f(bf16_t h) {
    union { unsigned int u; float f; } v; v.u = ((unsigned int)h) << 16; return v.f;
}
__device__ __forceinline__ bf16_t f2bf(float f) {
    union { float f; unsigned int u; } v; v.f = f;
    unsigned int r = (v.u + 0x7FFFu + ((v.u >> 16) & 1u)) >> 16;
    return (bf16_t)r;
}
__device__ __forceinline__ bf16x8 as_bf(us8 v) {
    union { us8 a; bf16x8 b; } u; u.a = v; return u.b;
}
__device__ __forceinline__ void gload16(const void* g, void* l) {
    __builtin_amdgcn_global_load_lds(
        (const __attribute__((address_space(1))) void*)g,
        (__attribute__((address_space(3))) void*)l, 16, 0, 0);
}

// Weight prep for ALL layers in one dispatch (+ zero page at the tail).
// Layout per layer: bf16 [9][KS][COTF][64 lanes][8].
__global__ __launch_bounds__(256) void wprep_all(
    const float* __restrict__ w1, const float* __restrict__ w2,
    const float* __restrict__ w3, const float* __restrict__ w4,
    const float* __restrict__ w5, const float* __restrict__ w6,
    bf16_t* __restrict__ dst)
{
    int i = blockIdx.x * 256 + threadIdx.x;
    if (i >= 350720) return;
    if (i >= 350208) { dst[i] = 0; return; }   // zero page
    const float* w; int Cout, Cin, COTF, KS, perm, base;
    if (i < 18432)       { w = w1; base = 0;      Cout = 64;  Cin = 5;   COTF = 4; KS = 1; perm = 0; }
    else if (i < 92160)  { w = w2; base = 18432;  Cout = 128; Cin = 64;  COTF = 8; KS = 2; perm = 0; }
    else if (i < 202752) { w = w3; base = 92160;  Cout = 81;  Cin = 128; COTF = 6; KS = 4; perm = 0; }
    else if (i < 294912) { w = w4; base = 202752; Cout = 64;  Cin = 160; COTF = 4; KS = 5; perm = 1; }
    else if (i < 331776) { w = w5; base = 294912; Cout = 64;  Cin = 64;  COTF = 4; KS = 2; perm = 0; }
    else                 { w = w6; base = 331776; Cout = 27;  Cin = 64;  COTF = 2; KS = 2; perm = 0; }
    int r = i - base;
    int j = r & 7;
    int lane = (r >> 3) & 63;
    int cot = (r >> 9) % COTF;
    int rest = r / (512 * COTF);      // = tap*KS + ks
    int ks = rest % KS, tap = rest / KS;
    int col = lane & 15, hi = lane >> 4;
    int co = cot * 16 + col;
    int ci = ks * 32 + hi * 8 + j;
    float v = 0.f;
    if (co < Cout && ci < Cin) {
        int rci = ci;
        if (perm) rci = (ci < 128) ? ci + 5 : (ci < 133 ? ci - 128 : ci);
        v = w[((size_t)co * Cin + rci) * 9 + tap];
    }
    dst[i] = f2bf(v);
}

// Pipelined LDS-staged implicit-GEMM 3x3 SAME conv, bf16 MFMA, batched
// over images via blockIdx.y = img*128 + yblk. Full-image slabs
// [C/32][512][512][32], per-image stride given.
// Block = 256 thr = 4 waves = 4 output rows x 64 px (wave = one row).
// Counted-vmcnt schedule: {ALOAD(ks) -> STAGE(ks+1)[7 newest vm] ->
// s_waitcnt vmcnt(7) -> s_barrier -> COMPUTE -> raw s_barrier}.
// SESSION LEDGER (8 isolated levers, all neutral or worse): counted
// ALOAD-in-flight vmcnt (R1) ~0; launch_bounds(256,3) VGPR 104->84
// scratch spill -2.7x (R2); y-persistent blocks L2 thrash -2x (R3);
// z-fold into x ~0 (R4); 16px-x-4row wave remap (LDS-read halving) ~0
// (R5); 3-buffer 2-slice lead -6% (R6); direct-load no-LDS -13% at 2x
// occupancy (R7). Per-layer rates: conv3(KS4) ~65% dense MFMA peak,
// ww1(KS5) ~54%, conv2(KS2) ~43% -- block wall is ~fixed ~21.5k cy
// (2-phase fill/drain), efficiency scales with K-depth per block.
// This is the 2-phase template plateau; exit = 8-phase co-design,
// out of safe scope here.
template<int COT, int KS>
__global__ __launch_bounds__(256, 2) void tconv(
    const bf16_t* __restrict__ in, size_t inImgStride,
    const bf16_t* __restrict__ wt, const float* __restrict__ bias,
    bf16_t* __restrict__ out, size_t outImgStride,
    int COTF, int Cout, int relu, const bf16_t* __restrict__ zp)
{
    __shared__ us8 buf[2][1584];
    const int tid = threadIdx.x;
    const int wave = tid >> 6, lane = tid & 63;
    const int col = lane & 15, hi = lane >> 4;
    const int img = blockIdx.y >> 7;
    const int yb0 = (blockIdx.y & 127) * 4;
    const int xb = blockIdx.x * 64;
    const int czbase = blockIdx.z * COT;
    const size_t slab = (size_t)HH * WW * 32;

    in += (size_t)img * inImgStride;
    out += (size_t)img * outImgStride;

    // Per-thread staging decomposition (fixed across slices).
    int gofs[7];
    bool ok[7];
#pragma unroll
    for (int k = 0; k < 7; ++k) {
        int u = tid + k * 256;
        if (u >= 1584) u = 1583;
        int row = (unsigned)u / 264u;
        int rem = u - row * 264;
        int px = rem >> 2, cs = rem & 3;
        int c = (cs - (px >> 1)) & 3;         // logical chunk stored at slot cs
        int yin = yb0 - 1 + row;
        int gx = xb - 1 + px;
        ok[k] = ((unsigned)yin < (unsigned)HH) && ((unsigned)gx < (unsigned)WW);
        gofs[k] = ok[k] ? (int)(((size_t)yin * WW + gx) * 32 + c * 8) : 0;
    }

    auto STAGE = [&](int nb, int ks) {
#pragma unroll
        for (int k = 0; k < 7; ++k) {
            if (k == 6 && tid >= 48) continue;     // 1584 = 6*256 + 48
            const bf16_t* g = ok[k] ? in + (size_t)ks * slab + gofs[k] : zp;
            gload16(g, (void*)&buf[nb][k * 256 + wave * 64]);
        }
    };

    f32x4 acc[4][COT] = {};
    bf16x8 a[9][COT];

    auto ALOAD = [&](int ks) {
#pragma unroll
        for (int t = 0; t < 9; ++t) {
#pragma unroll
            for (int c = 0; c < COT; ++c)
                a[t][c] = *(const bf16x8*)(wt
                    + (((size_t)t * KS + ks) * COTF + czbase + c) * 512 + lane * 8);
        }
    };

    auto COMPUTE = [&](int cb) {
#pragma unroll
        for (int dy = 0; dy < 3; ++dy) {
#pragma unroll
            for (int dx = 0; dx < 3; ++dx) {
                bf16x8 b[4];
#pragma unroll
                for (int pt = 0; pt < 4; ++pt) {
                    int X = pt * 16 + col + dx;
                    int unit = (wave + dy) * 264 + X * 4 + ((hi + (X >> 1)) & 3);
                    b[pt] = as_bf(buf[cb][unit]);
                }
#pragma unroll
                for (int c = 0; c < COT; ++c) {
#pragma unroll
                    for (int pt = 0; pt < 4; ++pt)
                        acc[pt][c] = __builtin_amdgcn_mfma_f32_16x16x32_bf16(
                            a[dy * 3 + dx][c], b[pt], acc[pt][c], 0, 0, 0);
                }
            }
        }
    };

    STAGE(0, 0);
    for (int ks = 0; ks < KS; ++ks) {
        ALOAD(ks);
        __builtin_amdgcn_sched_barrier(0);
        if (ks + 1 < KS) {
            STAGE((ks + 1) & 1, ks + 1);                // prefetch = 7 newest vm ops
            __builtin_amdgcn_sched_barrier(0);
            asm volatile("s_waitcnt vmcnt(7)" ::: "memory");   // A+stage(ks) done
        } else {
            asm volatile("s_waitcnt vmcnt(0)" ::: "memory");   // final drain
        }
        __builtin_amdgcn_sched_barrier(0);
        __builtin_amdgcn_s_barrier();        // staging(ks) visible to all waves
        __builtin_amdgcn_sched_barrier(0);
        COMPUTE(ks & 1);                     // prefetch(ks+1) in flight under MFMA
        __builtin_amdgcn_s_barrier();        // buf[ks&1] free for overwrite
        __builtin_amdgcn_sched_barrier(0);
    }

    // Epilogue: slab-layout NHWC-32 store; wave owns row y.
    int y = yb0 + wave;
#pragma unroll
    for (int c = 0; c < COT; ++c) {
        int chbase = (czbase + c) * 16 + hi * 4;
        int slice = chbase >> 5, rem = chbase & 31;
        float bv[4];
#pragma unroll
        for (int j = 0; j < 4; ++j) {
            int co = chbase + j;
            bv[j] = (co < Cout) ? bias[co] : 0.f;
        }
#pragma unroll
        for (int pt = 0; pt < 4; ++pt) {
            int x = xb + pt * 16 + col;
            us4 o;
#pragma unroll
            for (int j = 0; j < 4; ++j) {
                float v = acc[pt][c][j] + bv[j];
                if (relu) v = fmaxf(v, 0.f);
                o[j] = f2bf(v);
            }
            *(us4*)(out + (((size_t)slice * HH + y) * WW + x) * 32 + rem) = o;
        }
    }
}

// frames fp32 NCHW -> slab [1][512][512][32] bf16 (ch 0..4 used), batched
__global__ __launch_bounds__(256) void tr_fr32(
    const float* __restrict__ fr0, int img0,
    bf16_t* __restrict__ dst0, size_t stride)
{
    int img = blockIdx.y;
    int i = blockIdx.x * 256 + threadIdx.x;   // 0..262143, exact
    const float* fr = fr0 + (size_t)(img0 + img) * 5 * HWP;
    bf16_t* dst = dst0 + (size_t)img * stride;
    us8 v0 = {};
#pragma unroll
    for (int c = 0; c < 5; ++c) v0[c] = f2bf(fr[(size_t)c * HWP + i]);
    us8 z = {};
    us8* o = (us8*)(dst + (size_t)i * 32);
    o[0] = v0; o[1] = z; o[2] = z; o[3] = z;
}

// Fused sampler: trilinear 27-sample + frame-channel fill, full 32-ch
// vectorized output. IN-PLACE: cat slab == OF slab 0 (each thread reads
// its pixel's 96 offset channels BEFORE writing its pixel's 32 cat
// channels; no cross-pixel dependence, so the overwrite is safe).
__global__ __launch_bounds__(256, 4) void sample27f(
    const float* __restrict__ fr0, int img0,
    const bf16_t* __restrict__ of0, size_t stride,
    bf16_t* __restrict__ cat0)
{
    int img = blockIdx.y;
    int i = blockIdx.x * 256 + threadIdx.x;
    int y = i >> 9, x = i & 511;
    const float* f = fr0 + (size_t)(img0 + img) * 5 * HWP;
    const bf16_t* off = of0 + (size_t)img * stride;
    bf16_t* cat = cat0 + (size_t)img * stride;

    us8 ov[12];
#pragma unroll
    for (int sl = 0; sl < 3; ++sl)
#pragma unroll
        for (int c = 0; c < 4; ++c)
            ov[sl * 4 + c] = *(const us8*)(off
                + (((size_t)sl * HH + y) * WW + x) * 32 + c * 8);

    us8 outv[4];
#pragma unroll
    for (int c = 0; c < 5; ++c)
        outv[0][c] = f2bf(f[(size_t)c * HWP + i]);

#pragma unroll
    for (int s = 0; s < 27; ++s) {
        float dt  = bf2f((bf16_t)ov[(3 * s) >> 3][(3 * s) & 7]);
        float dyo = bf2f((bf16_t)ov[(3 * s + 1) >> 3][(3 * s + 1) & 7]);
        float dxo = bf2f((bf16_t)ov[(3 * s + 2) >> 3][(3 * s + 2) & 7]);
        float tc = dt + (float)(s / 9 + 1);
        float yc = dyo + (float)((s / 3) % 3 - 1) + (float)y;
        float xc = dxo + (float)(s % 3 - 1) + (float)x;
        tc = fminf(fmaxf(tc, 0.f), 4.f);
        yc = fminf(fmaxf(yc, 0.f), 511.f);
        xc = fminf(fmaxf(xc, 0.f), 511.f);
        float t0f = floorf(tc), y0f = floorf(yc), x0f = floorf(xc);
        float wt = tc - t0f, wy = yc - y0f, wx = xc - x0f;
        int t0 = (int)t0f, y0 = (int)y0f, x0 = (int)x0f;
        int t1 = min(t0 + 1, 4), y1 = min(y0 + 1, 511), x1 = min(x0 + 1, 511);
        float c000 = f[((size_t)t0 * HH + y0) * WW + x0];
        float c001 = f[((size_t)t0 * HH + y0) * WW + x1];
        float c010 = f[((size_t)t0 * HH + y1) * WW + x0];
        float c011 = f[((size_t)t0 * HH + y1) * WW + x1];
        float c100 = f[((size_t)t1 * HH + y0) * WW + x0];
        float c101 = f[((size_t)t1 * HH + y0) * WW + x1];
        float c110 = f[((size_t)t1 * HH + y1) * WW + x0];
        float c111 = f[((size_t)t1 * HH + y1) * WW + x1];
        float c00 = c000 * (1.f - wx) + c001 * wx;
        float c01 = c010 * (1.f - wx) + c011 * wx;
        float c10 = c100 * (1.f - wx) + c101 * wx;
        float c11 = c110 * (1.f - wx) + c111 * wx;
        float c0 = c00 * (1.f - wy) + c01 * wy;
        float c1 = c10 * (1.f - wy) + c11 * wy;
        int ch = 5 + s;
        outv[ch >> 3][ch & 7] = f2bf(c0 * (1.f - wt) + c1 * wt);
    }

    us8* o = (us8*)(cat + ((size_t)y * WW + x) * 32);
    o[0] = outv[0]; o[1] = outv[1]; o[2] = outv[2]; o[3] = outv[3];
}

__global__ __launch_bounds__(256) void combineN(
    const bf16_t* __restrict__ cat0, const bf16_t* __restrict__ wg0,
    size_t stride, float* __restrict__ out, int img0)
{
    int img = blockIdx.y;
    int i = blockIdx.x * 256 + threadIdx.x;
    int gimg = img0 + img;
    const bf16_t* sp = cat0 + (size_t)img * stride + (size_t)i * 32 + 5;
    const bf16_t* wp = wg0 + (size_t)img * stride + (size_t)i * 32;
    float* ogp  = out + (size_t)gimg * 4 * HWP;
    float* oavg = out + (size_t)16 * HWP + (size_t)gimg * HWP;
    float total = 0.f;
#pragma unroll
    for (int g = 0; g < 4; ++g) {
        float acc = 0.f;
#pragma unroll
        for (int j = 0; j < 6; ++j)
            acc += bf2f(sp[g * 6 + j]) * bf2f(wp[g * 6 + j]);
        float gp = 4.f * acc;
        ogp[(size_t)g * HWP + i] = gp;
        total += gp;
    }
    oavg[i] = total / 27.f;
}

static inline int cdiv(int a, int b) { return (a + b - 1) / b; }

extern "C" void kernel_launch(void* const* d_in, const int* in_sizes, int n_in,
                              void* d_out, int out_size, void* d_ws, size_t ws_size,
                              hipStream_t stream)
{
    const float* frames = (const float*)d_in[0];
    const float* ow1 = (const float*)d_in[1];
    const float* ob1 = (const float*)d_in[2];
    const float* ow2 = (const float*)d_in[3];
    const float* ob2 = (const float*)d_in[4];
    const float* ow3 = (const float*)d_in[5];
    const float* ob3 = (const float*)d_in[6];
    const float* ww1 = (const float*)d_in[7];
    const float* wb1 = (const float*)d_in[8];
    const float* ww2 = (const float*)d_in[9];
    const float* wb2 = (const float*)d_in[10];
    const float* ww3 = (const float*)d_in[11];
    const float* wb3 = (const float*)d_in[12];
    float* out = (float*)d_out;

    bf16_t* Wp = (bf16_t*)d_ws;
    const size_t wo1 = 0;          // conv1: KS1 COTF4
    const size_t wo2 = 18432;      // conv2: KS2 COTF8
    const size_t wo3 = 92160;      // conv3: KS4 COTF6
    const size_t wo4 = 202752;     // ww1:   KS5 COTF4
    const size_t wo5 = 294912;     // ww2:   KS2 COTF4
    const size_t wo6 = 331776;     // ww3:   KS2 COTF2
    const size_t wzp = 350208;     // zero page (1 KB)
    const size_t wtot = 350720;

    // 7-slab aliased per-image workspace (liveness-verified):
    //   S0..S3: feat (conv2 out) -> W2 (S0..S1), WG (S2)
    //   S4..S6: F1 (S4..S5), FR (S6) -> OF (S4..S6) -> cat (S4, in-place
    //           sampler) / W1 (S5..S6)
    //   ww1 input = S0..S4 contiguous (feat 4 slabs + cat slab).
    const size_t SLAB = (size_t)HH * WW * 32;           // 8,388,608 elems
    const size_t PerImg = 7 * SLAB;                     // 58,720,256 elems

    size_t availElems = ws_size / sizeof(bf16_t);
    int NB = 1;
    if (wtot + 4 * PerImg <= availElems) NB = 4;
    else if (wtot + 2 * PerImg <= availElems) NB = 2;

    bf16_t* ZP = Wp + wzp;
    bf16_t* WS = Wp + wtot;

    wprep_all<<<cdiv(350720, 256), 256, 0, stream>>>(ow1, ow2, ow3, ww1, ww2, ww3, Wp);

    for (int s = 0; s < 4; s += NB) {
        int nb = (4 - s < NB) ? (4 - s) : NB;
        bf16_t* S0 = WS;                 // feat / W2 / WG region
        bf16_t* S2 = WS + 2 * SLAB;      // WG
        bf16_t* S4 = WS + 4 * SLAB;      // F1 / OF / cat
        bf16_t* S5 = WS + 5 * SLAB;      // W1
        bf16_t* S6 = WS + 6 * SLAB;      // FR

        // frames -> FR (S6)
        tr_fr32<<<dim3(1024, nb), 256, 0, stream>>>(frames, s, S6, PerImg);
        // conv1: FR 32(pad5) (S6) -> F1 64 (S4..S5)
        tconv<4, 1><<<dim3(8, 128 * nb, 1), 256, 0, stream>>>(
            S6, PerImg, Wp + wo1, ob1, S4, PerImg, 4, 64, 1, ZP);
        // conv2: F1 64 (S4..S5) -> feat 128 (S0..S3), z-split co
        tconv<4, 2><<<dim3(8, 128 * nb, 2), 256, 0, stream>>>(
            S4, PerImg, Wp + wo2, ob2, S0, PerImg, 8, 128, 1, ZP);
        // conv3: feat 128 -> offsets 81(pad96) (S4..S6), no relu, z-split co
        tconv<3, 4><<<dim3(8, 128 * nb, 2), 256, 0, stream>>>(
            S0, PerImg, Wp + wo3, ob3, S4, PerImg, 6, 81, 0, ZP);
        // fused sampler (+frame fill) -> cat slab IN-PLACE over OF slab 0 (S4)
        sample27f<<<dim3(1024, nb), 256, 0, stream>>>(frames, s, S4, PerImg, S4);
        // ww1: cat 160 (S0..S4, 5 slabs) -> W1 64 (S5..S6)
        tconv<4, 5><<<dim3(8, 128 * nb, 1), 256, 0, stream>>>(
            S0, PerImg, Wp + wo4, wb1, S5, PerImg, 4, 64, 1, ZP);
        // ww2: W1 64 (S5..S6) -> W2 64 (S0..S1)
        tconv<4, 2><<<dim3(8, 128 * nb, 1), 256, 0, stream>>>(
            S5, PerImg, Wp + wo5, wb2, S0, PerImg, 4, 64, 1, ZP);
        // ww3: W2 64 (S0..S1) -> WG 27(pad32) (S2)
        tconv<2, 2><<<dim3(8, 128 * nb, 1), 256, 0, stream>>>(
            S0, PerImg, Wp + wo6, wb3, S2, PerImg, 2, 27, 1, ZP);
        // fusion: cat (S4) x WG (S2) -> out
        combineN<<<dim3(1024, nb), 256, 0, stream>>>(S4, S2, PerImg, out, s);
    }
}